// Round 15
// baseline (898.601 us; speedup 1.0000x reference)
//
#include <hip/hip_runtime.h>
#include <hip/hip_bf16.h>
#include <stdint.h>

#define NB 16
#define NP 4096
#define NSP 1024      // npoint
#define KNN 32        // nsample
#define PTOT (NB*NSP*KNN)      // 524288 rows
#define NTILES (PTOT/16)       // 32768 M-tiles
#define GRID_FG 256            // fps+gather fused grid: 1 block/CU, fps gets DEDICATED CUs
#define GWORK (NB*NSP/4)       // 4096 gather work items (4 centers each)

typedef __attribute__((ext_vector_type(8))) short short8;
typedef __attribute__((ext_vector_type(4))) float f32x4;
typedef __attribute__((ext_vector_type(2))) float f32x2;

__device__ __forceinline__ float fadd_(float a,float b){return __fadd_rn(a,b);}
__device__ __forceinline__ float fmul_(float a,float b){return __fmul_rn(a,b);}
__device__ __forceinline__ float fsub_(float a,float b){return __fsub_rn(a,b);}

__device__ __forceinline__ float bf2f(unsigned short u){
    unsigned int x = ((unsigned int)u) << 16; float f; __builtin_memcpy(&f,&x,4); return f;
}
__device__ __forceinline__ unsigned short f2bf(float f){
    unsigned int x; __builtin_memcpy(&x,&f,4);
    x = x + 0x7fffu + ((x>>16)&1u);
    return (unsigned short)(x>>16);
}

// f32 max step via DPP (identity 0 for invalid lanes is safe: distances >= 0).
template<int CTRL>
__device__ __forceinline__ float dpp_fmax_step(float v){
    int d = __builtin_amdgcn_update_dpp(0, __float_as_int(v), CTRL, 0xF, 0xF, true);
    return fmaxf(v, __int_as_float(d));
}

// per-channel BN stats -> (A, B); verbatim the retired finalize_kernel math.
__device__ __forceinline__ void ab_from_stats(const double* __restrict__ st, const float* __restrict__ g,
    const float* __restrict__ beta, int o, float* A_out, float* B_out)
{
    double s=0.0, q=0.0;
#pragma unroll
    for (int slot=0;slot<8;slot++){
        s += st[(size_t)(slot*2+0)*128+o];
        q += st[(size_t)(slot*2+1)*128+o];
    }
    const double cnt = (double)PTOT;
    float mean = (float)(s/cnt);
    float var  = (float)(q/cnt - (s/cnt)*(s/cnt));
    float inv  = rsqrtf(var + 1e-5f);
    float A = g[o]*inv;
    *A_out = A; *B_out = beta[o] - mean*A;
}

// ---------------------------------------------------------------- fused FPS + ball-gather (v17)
// v16 counters: dedicated CUs (grid=256) recovered 50us but fps still +92us
// over standalone 618. Mechanism: per-step agent-scope publish stores by the
// fps wave must get their CONTENDED-L2 ack at each step's barrier vmcnt(0)
// drain (idle-L2 cost was ~5us [v5->v7]; with 240 gather blocks hammering L2
// it is ~90us). v17: batch the publish — per step only an LDS ring write;
// every 32 steps a 32-lane burst store + ONE barrier drain + tid0 release of
// progress (same progress values 32,64,..,1024; barrier guarantees pub
// visibility before release -> protocol semantics identical to verified
// v16). Poll backoff s_sleep 32->127 cuts acquire-poll L2 traffic 4x.
__global__ __launch_bounds__(256,1) void fps_gather_kernel(const float* __restrict__ xyz,
    const float* __restrict__ pts, float* __restrict__ out0,
    unsigned short* __restrict__ feat,
    unsigned long long* __restrict__ pubXY, unsigned* __restrict__ pubZ,
    unsigned* __restrict__ progress)
{
    __shared__ __align__(16) char smem[65536 + 64 + NSP*4 + 512];
    const int tid = threadIdx.x;
    const int lane = tid & 63, wv = tid >> 6;

    if (blockIdx.x < NB){
        // ================= FPS branch (batch b, dedicated CU) =================
        const int b = blockIdx.x;
        const float* xb = xyz + (size_t)b*3*NP;
        float4* sp = (float4*)smem;                              // 64 KB
        unsigned long long* kslots = (unsigned long long*)(smem + 65536);  // [2][4]
        int* lds_far = (int*)(smem + 65536 + 64);                // NSP ints
        float4* cring = (float4*)(smem + 65536 + 64 + NSP*4);    // 32-entry centroid ring
        f32x2 px[8], py[8], pz[8], pd2[8];
        const int base = tid*16;
#pragma unroll
        for (int j=0;j<16;j+=4){
            float4 vx = *(const float4*)(xb + base + j);
            float4 vy = *(const float4*)(xb + NP + base + j);
            float4 vz = *(const float4*)(xb + 2*NP + base + j);
            px[j/2]   = (f32x2){vx.x,vx.y}; px[j/2+1] = (f32x2){vx.z,vx.w};
            py[j/2]   = (f32x2){vy.x,vy.y}; py[j/2+1] = (f32x2){vy.z,vy.w};
            pz[j/2]   = (f32x2){vz.x,vz.y}; pz[j/2+1] = (f32x2){vz.z,vz.w};
            sp[base+j+0] = make_float4(vx.x,vy.x,vz.x,0.f);
            sp[base+j+1] = make_float4(vx.y,vy.y,vz.y,0.f);
            sp[base+j+2] = make_float4(vx.z,vy.z,vz.z,0.f);
            sp[base+j+3] = make_float4(vx.w,vy.w,vz.w,0.f);
            pd2[j/2]   = (f32x2){1e10f,1e10f};
            pd2[j/2+1] = (f32x2){1e10f,1e10f};
        }
        __syncthreads();
        int far = 0;
        float cx, cy, cz;
        { float4 c0 = sp[0]; cx=c0.x; cy=c0.y; cz=c0.z; }
        for (int s=0;s<NSP;s++){
            if (tid == (s & 255)) lds_far[s] = far;
            // batched publish: centers s-32..s-1 (ring written in prior steps,
            // visible via their end-of-step barriers). Condition is uniform.
            if ((s & 31) == 0 && s > 0){
                if (tid < 32){
                    float4 c = cring[tid];
                    unsigned long long xy = ((unsigned long long)__float_as_uint(c.y)<<32)
                                          | (unsigned long long)__float_as_uint(c.x);
                    __hip_atomic_store(&pubXY[b*NSP + (s-32) + tid], xy, __ATOMIC_RELAXED, __HIP_MEMORY_SCOPE_AGENT);
                    __hip_atomic_store(&pubZ [b*NSP + (s-32) + tid], __float_as_uint(c.z), __ATOMIC_RELAXED, __HIP_MEMORY_SCOPE_AGENT);
                }
                __syncthreads();   // drains vmcnt: pub stores complete before release
                if (tid == 0)
                    __hip_atomic_store(&progress[b*16], (unsigned)s, __ATOMIC_RELEASE, __HIP_MEMORY_SCOPE_AGENT);
            }
            if (tid == 255) cring[s & 31] = make_float4(cx, cy, cz, 0.f);
            f32x2 bm2 = (f32x2){-1.f,-1.f};
            {
#pragma clang fp contract(off)
                const f32x2 cx2 = (f32x2){cx,cx}, cy2 = (f32x2){cy,cy}, cz2 = (f32x2){cz,cz};
#pragma unroll
                for (int k=0;k<8;k++){
                    f32x2 dx = px[k]-cx2, dy = py[k]-cy2, dz = pz[k]-cz2;
                    f32x2 d  = (dx*dx + dy*dy) + dz*dz;
                    pd2[k] = __builtin_elementwise_min(pd2[k], d);
                    bm2    = __builtin_elementwise_max(bm2, pd2[k]);
                }
            }
            float bd = fmaxf(bm2.x, bm2.y);
            float m = bd;
            m = dpp_fmax_step<0x111>(m);   // row_shr:1
            m = dpp_fmax_step<0x112>(m);   // row_shr:2
            m = dpp_fmax_step<0x114>(m);   // row_shr:4
            m = dpp_fmax_step<0x118>(m);   // row_shr:8
            m = dpp_fmax_step<0x142>(m);   // row_bcast:15
            m = dpp_fmax_step<0x143>(m);   // row_bcast:31  -> lane 63 has wave max
            const float wm = __int_as_float(__builtin_amdgcn_readlane(__float_as_int(m), 63));
            int il = 0;
#pragma unroll
            for (int k=7;k>=0;k--){
                if (pd2[k].y == wm) il = 2*k+1;
                if (pd2[k].x == wm) il = 2*k;
            }
            unsigned long long wmask = __ballot(bd == wm);   // nonempty by construction
            int L = __ffsll(wmask) - 1;                      // lowest lane = smallest idx
            int widx = __builtin_amdgcn_readlane(base + il, L);
            unsigned long long key = ((unsigned long long)__float_as_uint(wm) << 32)
                                   | (unsigned int)(NP-1-widx);
            if (lane==0) kslots[(s&1)*4 + wv] = key;
            __syncthreads();
            {
                const unsigned long long* sl = kslots + (s&1)*4;
                unsigned long long a0 = sl[0], a1 = sl[1], a2 = sl[2], a3 = sl[3];
                unsigned long long m0 = a0>a1?a0:a1, m1 = a2>a3?a2:a3;
                unsigned long long mx = m0>m1?m0:m1;
                far = NP-1-(int)(mx & 0xFFFFFFFFu);
            }
            float4 c = sp[far]; cx=c.x; cy=c.y; cz=c.z;
        }
        // publish the final 32 centers (steps NSP-32..NSP-1; ring pos 0..31)
        if (tid < 32){
            float4 c = cring[tid];
            unsigned long long xy = ((unsigned long long)__float_as_uint(c.y)<<32)
                                  | (unsigned long long)__float_as_uint(c.x);
            __hip_atomic_store(&pubXY[b*NSP + (NSP-32) + tid], xy, __ATOMIC_RELAXED, __HIP_MEMORY_SCOPE_AGENT);
            __hip_atomic_store(&pubZ [b*NSP + (NSP-32) + tid], __float_as_uint(c.z), __ATOMIC_RELAXED, __HIP_MEMORY_SCOPE_AGENT);
        }
        __syncthreads();
        if (tid==0)
            __hip_atomic_store(&progress[b*16], (unsigned)NSP, __ATOMIC_RELEASE, __HIP_MEMORY_SCOPE_AGENT);
        for (int i=tid;i<NSP;i+=256){
            int id = lds_far[i];
            float4 c = sp[id];
            out0[(size_t)b*3*NSP + i]         = c.x;
            out0[(size_t)b*3*NSP + NSP + i]   = c.y;
            out0[(size_t)b*3*NSP + 2*NSP + i] = c.z;
        }
        return;
    }

    // ================= gather branch (240 workers on their own CUs) =================
    int* gslots = ((int*)smem) + wv*32;   // wave-private slot row
    const int gblk = blockIdx.x - NB;     // 0..239
    const float R2 = (float)(0.4*0.4);    // must round via double: 0.4f*0.4f differs!
    for (int j = gblk; j < GWORK; j += (GRID_FG - NB)){
        const int ord = j*4 + wv;
        const int s = ord >> 4, b = ord & 15;       // s-major: waits track publish order
        const int center = b*NSP + s;
        // wait for availability (progress[b] > s); long sleep = less L2 poll traffic
        for (;;){
            unsigned p = __hip_atomic_load(&progress[b*16], __ATOMIC_ACQUIRE, __HIP_MEMORY_SCOPE_AGENT);
            if (p > (unsigned)s) break;
            __builtin_amdgcn_s_sleep(127);
        }
        unsigned long long xy = __hip_atomic_load(&pubXY[center], __ATOMIC_RELAXED, __HIP_MEMORY_SCOPE_AGENT);
        unsigned zb           = __hip_atomic_load(&pubZ[center],  __ATOMIC_RELAXED, __HIP_MEMORY_SCOPE_AGENT);
        const float cx = __uint_as_float((unsigned)xy);
        const float cy = __uint_as_float((unsigned)(xy>>32));
        const float cz = __uint_as_float(zb);
        const float* xb = xyz + (size_t)b*3*NP;
        const float* pb = pts + (size_t)b*6*NP;
        const float src2 = fadd_(fadd_(fmul_(cx,cx),fmul_(cy,cy)),fmul_(cz,cz));
        int total = 0;
        for (int c0=0;c0<NP;c0+=64){
            const int i = c0 + lane;
            float x=xb[i], y=xb[NP+i], z=xb[2*NP+i];
            float dot  = fadd_(fadd_(fmul_(cx,x),fmul_(cy,y)),fmul_(cz,z));
            float dst2 = fadd_(fadd_(fmul_(x,x),fmul_(y,y)),fmul_(z,z));
            float d = fadd_(fadd_(fmul_(-2.0f,dot), src2), dst2);
            bool pred = !(d > R2);
            unsigned long long m = __ballot(pred);
            int pos = total + (int)__popcll(m & ((1ull<<lane)-1ull));
            if (pred && pos < 32) gslots[pos] = i;
            total += (int)__popcll(m);
            if (total >= 32) break;
        }
        const int nvalid = total < 32 ? total : 32;
        const int n = lane & 31;
        const int idx = gslots[ (n < nvalid) ? n : 0 ];
        unsigned short* fr = feat + (size_t)center*KNN*32 + (size_t)n*32;
        if (lane < 32){
            float gx = fsub_(xb[idx], cx), gy = fsub_(xb[NP+idx], cy), gz = fsub_(xb[2*NP+idx], cz);
            float p0=pb[idx], p1=pb[NP+idx], p2=pb[2*NP+idx], p3=pb[3*NP+idx], p4=pb[4*NP+idx];
            short8 v;
            v[0]=(short)f2bf(gx); v[1]=(short)f2bf(gy); v[2]=(short)f2bf(gz);
            v[3]=(short)f2bf(p0); v[4]=(short)f2bf(p1); v[5]=(short)f2bf(p2);
            v[6]=(short)f2bf(p3); v[7]=(short)f2bf(p4);
            *(short8*)fr = v;
        } else {
            float p5 = pb[5*NP+idx];
            short8 v = (short8){0,0,0,0,0,0,0,0};
            v[0]=(short)f2bf(p5);
            *(short8*)(fr+8)  = v;
            short8 z8 = (short8){0,0,0,0,0,0,0,0};
            *(short8*)(fr+16) = z8;
            *(short8*)(fr+24) = z8;
        }
    }
}

// ---------------------------------------------------------------- conv + stats (MFMA)
// h = in@W^T + bias. Optional input normalization relu(x*A+B) fused in prologue,
// with (A,B) computed in-kernel from the previous layer's stats.
template<int KT,int OT,bool NORM_IN,bool STORE_H>
__global__ __launch_bounds__(256,1) void conv_kernel(const unsigned short* __restrict__ in,
    const unsigned short* __restrict__ wp, const float* __restrict__ bias,
    const double* __restrict__ stats_in, const float* __restrict__ gin,
    const float* __restrict__ bein,
    unsigned short* __restrict__ h_out, double* __restrict__ stats)
{
    constexpr int K = KT*32, O = OT*16;
    const int lane = threadIdx.x & 63, wv = threadIdx.x >> 6;
    const int col = lane & 15, quad = lane >> 4;
    __shared__ float sA[128], sB[128];
    if constexpr (NORM_IN){
        if ((int)threadIdx.x < K){
            float A, B;
            ab_from_stats(stats_in, gin, bein, threadIdx.x, &A, &B);
            sA[threadIdx.x] = A; sB[threadIdx.x] = B;
        }
        __syncthreads();
    }
    short8 bf[OT][KT];
#pragma unroll
    for (int t=0;t<OT;t++)
#pragma unroll
        for (int kt=0;kt<KT;kt++)
            bf[t][kt] = *(const short8*)(wp + (size_t)(t*16+col)*K + kt*32 + quad*8);
    float brow[OT];
#pragma unroll
    for (int t=0;t<OT;t++) brow[t] = bias[t*16+col];
    float nA[KT*8], nB[KT*8];
    if constexpr (NORM_IN){
#pragma unroll
        for (int kt=0;kt<KT;kt++)
#pragma unroll
            for (int j=0;j<8;j++){
                int c = kt*32+quad*8+j;
                nA[kt*8+j]=sA[c]; nB[kt*8+j]=sB[c];
            }
    }
    float ssum[OT], ssq[OT];
#pragma unroll
    for (int t=0;t<OT;t++){ ssum[t]=0.f; ssq[t]=0.f; }
    const int gw = blockIdx.x*4 + wv, nw = gridDim.x*4;
    for (int tile=gw; tile<NTILES; tile+=nw){
        const int row0 = tile*16;
        short8 af[KT];
#pragma unroll
        for (int kt=0;kt<KT;kt++){
            af[kt] = *(const short8*)(in + (size_t)(row0+col)*K + kt*32 + quad*8);
            if constexpr (NORM_IN){
#pragma unroll
                for (int j=0;j<8;j++){
                    float x = bf2f((unsigned short)af[kt][j]);
                    x = fmaxf(x*nA[kt*8+j]+nB[kt*8+j], 0.f);
                    af[kt][j] = (short)f2bf(x);
                }
            }
        }
        f32x4 acc[OT];
#pragma unroll
        for (int t=0;t<OT;t++) acc[t] = (f32x4){0.f,0.f,0.f,0.f};
#pragma unroll
        for (int kt=0;kt<KT;kt++)
#pragma unroll
            for (int t=0;t<OT;t++)
                acc[t] = __builtin_amdgcn_mfma_f32_16x16x32_bf16(af[kt], bf[t][kt], acc[t], 0,0,0);
#pragma unroll
        for (int t=0;t<OT;t++){
#pragma unroll
            for (int r=0;r<4;r++){
                float h = acc[t][r] + brow[t];
                if constexpr (STORE_H)
                    h_out[(size_t)(row0 + quad*4 + r)*O + t*16 + col] = f2bf(h);
                ssum[t] += h; ssq[t] = fmaf(h,h,ssq[t]);
            }
        }
    }
    __shared__ float bsum[128], bssq[128];
    for (int i=threadIdx.x;i<128;i+=256){ bsum[i]=0.f; bssq[i]=0.f; }
    __syncthreads();
#pragma unroll
    for (int t=0;t<OT;t++){
        float v = ssum[t]; v += __shfl_xor(v,16,64); v += __shfl_xor(v,32,64);
        float q = ssq[t];  q += __shfl_xor(q,16,64); q += __shfl_xor(q,32,64);
        if (quad==0){ atomicAdd(&bsum[t*16+col], v); atomicAdd(&bssq[t*16+col], q); }
    }
    __syncthreads();
    if ((int)threadIdx.x < O){
        const int slot = blockIdx.x & 7;
        atomicAdd(&stats[(size_t)(slot*2+0)*128 + threadIdx.x], (double)bsum[threadIdx.x]);
        atomicAdd(&stats[(size_t)(slot*2+1)*128 + threadIdx.x], (double)bssq[threadIdx.x]);
    }
}

// ---------------------------------------------------------------- fused layer0+layer1 (h0 never touches HBM)
__global__ __launch_bounds__(256,1) void conv01_kernel(
    const unsigned short* __restrict__ feat,
    const unsigned short* __restrict__ wp0, const float* __restrict__ b0v,
    const double* __restrict__ stats0, const float* __restrict__ g0v,
    const float* __restrict__ be0v,
    const unsigned short* __restrict__ wp1, const float* __restrict__ b1v,
    unsigned short* __restrict__ h1_out, double* __restrict__ stats1)
{
    const int lane = threadIdx.x & 63, wv = threadIdx.x >> 6;
    const int col = lane & 15, quad = lane >> 4;
    __shared__ float sA[64], sB[64];
    __shared__ unsigned short scratch[4][16*72];    // per-wave 16 rows x 72 ch (pad)
    if ((int)threadIdx.x < 64){
        float A, B;
        ab_from_stats(stats0, g0v, be0v, threadIdx.x, &A, &B);
        sA[threadIdx.x] = A; sB[threadIdx.x] = B;
    }
    __syncthreads();
    short8 bf0[4];
#pragma unroll
    for (int t=0;t<4;t++)
        bf0[t] = *(const short8*)(wp0 + (size_t)(t*16+col)*32 + quad*8);
    short8 bf1[4][2];
#pragma unroll
    for (int t=0;t<4;t++)
#pragma unroll
        for (int kt=0;kt<2;kt++)
            bf1[t][kt] = *(const short8*)(wp1 + (size_t)(t*16+col)*64 + kt*32 + quad*8);
    float b0row[4], n0A[4], n0B[4], b1row[4];
#pragma unroll
    for (int t=0;t<4;t++){
        b0row[t] = b0v[t*16+col];
        n0A[t]   = sA[t*16+col];
        n0B[t]   = sB[t*16+col];
        b1row[t] = b1v[t*16+col];
    }
    float ssum[4], ssq[4];
#pragma unroll
    for (int t=0;t<4;t++){ ssum[t]=0.f; ssq[t]=0.f; }
    unsigned short* sw = scratch[wv];
    const int gw = blockIdx.x*4 + wv, nw = gridDim.x*4;
    for (int tile=gw; tile<NTILES; tile+=nw){
        const int row0 = tile*16;
        short8 af0 = *(const short8*)(feat + (size_t)(row0+col)*32 + quad*8);
        f32x4 acc0[4];
#pragma unroll
        for (int t=0;t<4;t++) acc0[t] = (f32x4){0.f,0.f,0.f,0.f};
#pragma unroll
        for (int t=0;t<4;t++)
            acc0[t] = __builtin_amdgcn_mfma_f32_16x16x32_bf16(af0, bf0[t], acc0[t], 0,0,0);
#pragma unroll
        for (int t=0;t<4;t++)
#pragma unroll
            for (int r=0;r<4;r++){
                float h = acc0[t][r] + b0row[t];
                unsigned short hb = f2bf(h);               // = old h0 store
                float x = fmaxf(bf2f(hb)*n0A[t] + n0B[t], 0.f);
                sw[(quad*4+r)*72 + t*16 + col] = f2bf(x);  // = old conv2 repack
            }
        short8 af1[2];
        af1[0] = *(const short8*)(&sw[(size_t)col*72 + quad*8]);
        af1[1] = *(const short8*)(&sw[(size_t)col*72 + 32 + quad*8]);
        f32x4 acc1[4];
#pragma unroll
        for (int t=0;t<4;t++) acc1[t] = (f32x4){0.f,0.f,0.f,0.f};
#pragma unroll
        for (int kt=0;kt<2;kt++)
#pragma unroll
            for (int t=0;t<4;t++)
                acc1[t] = __builtin_amdgcn_mfma_f32_16x16x32_bf16(af1[kt], bf1[t][kt], acc1[t], 0,0,0);
#pragma unroll
        for (int t=0;t<4;t++)
#pragma unroll
            for (int r=0;r<4;r++){
                float h = acc1[t][r] + b1row[t];
                h1_out[(size_t)(row0 + quad*4 + r)*64 + t*16 + col] = f2bf(h);
                ssum[t] += h; ssq[t] = fmaf(h,h,ssq[t]);
            }
    }
    __shared__ float bsum[64], bssq[64];
    for (int i=threadIdx.x;i<64;i+=256){ bsum[i]=0.f; bssq[i]=0.f; }
    __syncthreads();
#pragma unroll
    for (int t=0;t<4;t++){
        float v = ssum[t]; v += __shfl_xor(v,16,64); v += __shfl_xor(v,32,64);
        float q = ssq[t];  q += __shfl_xor(q,16,64); q += __shfl_xor(q,32,64);
        if (quad==0){ atomicAdd(&bsum[t*16+col], v); atomicAdd(&bssq[t*16+col], q); }
    }
    __syncthreads();
    if ((int)threadIdx.x < 64){
        const int slot = blockIdx.x & 7;
        atomicAdd(&stats1[(size_t)(slot*2+0)*128 + threadIdx.x], (double)bsum[threadIdx.x]);
        atomicAdd(&stats1[(size_t)(slot*2+1)*128 + threadIdx.x], (double)bssq[threadIdx.x]);
    }
}

// ---------------------------------------------------------------- layer2 recompute + norm + relu + maxpool
__global__ __launch_bounds__(256,1) void conv_final_kernel(const unsigned short* __restrict__ in,
    const unsigned short* __restrict__ wp, const float* __restrict__ bias,
    const double* __restrict__ stats1, const float* __restrict__ g1v,
    const float* __restrict__ be1v,
    const double* __restrict__ stats2, const float* __restrict__ g2v,
    const float* __restrict__ be2v,
    float* __restrict__ out1)
{
    constexpr int KT=2, OT=8, K=64;
    const int lane = threadIdx.x & 63, wv = threadIdx.x >> 6;
    const int col = lane & 15, quad = lane >> 4;
    __shared__ float sInA[64], sInB[64], sOutA[128], sOutB[128];
    {
        const int t0 = threadIdx.x;
        if (t0 < 128){
            float A, B;
            ab_from_stats(stats2, g2v, be2v, t0, &A, &B);
            sOutA[t0] = A; sOutB[t0] = B;
        } else if (t0 < 192){
            float A, B;
            ab_from_stats(stats1, g1v, be1v, t0-128, &A, &B);
            sInA[t0-128] = A; sInB[t0-128] = B;
        }
        __syncthreads();
    }
    short8 bf[OT][KT];
#pragma unroll
    for (int t=0;t<OT;t++)
#pragma unroll
        for (int kt=0;kt<KT;kt++)
            bf[t][kt] = *(const short8*)(wp + (size_t)(t*16+col)*K + kt*32 + quad*8);
    float brow[OT], oA[OT], oB[OT];
#pragma unroll
    for (int t=0;t<OT;t++){
        brow[t] = bias[t*16+col];
        oA[t] = sOutA[t*16+col];
        oB[t] = sOutB[t*16+col];
    }
    float nA[16], nB[16];
#pragma unroll
    for (int kt=0;kt<2;kt++)
#pragma unroll
        for (int j=0;j<8;j++){
            int c = kt*32+quad*8+j;
            nA[kt*8+j]=sInA[c]; nB[kt*8+j]=sInB[c];
        }
    const int gw = blockIdx.x*4 + wv, nw = gridDim.x*4;
    for (int grp=gw; grp<NB*NSP; grp+=nw){
        float vmax[OT];
#pragma unroll
        for (int t=0;t<OT;t++) vmax[t]=0.f;
#pragma unroll
        for (int mt=0; mt<2; mt++){
            const int row0 = grp*32 + mt*16;
            short8 af[KT];
#pragma unroll
            for (int kt=0;kt<2;kt++){
                af[kt] = *(const short8*)(in + (size_t)(row0+col)*K + kt*32 + quad*8);
#pragma unroll
                for (int j=0;j<8;j++){
                    float x = bf2f((unsigned short)af[kt][j]);
                    x = fmaxf(x*nA[kt*8+j]+nB[kt*8+j], 0.f);
                    af[kt][j] = (short)f2bf(x);
                }
            }
            f32x4 acc[OT];
#pragma unroll
            for (int t=0;t<OT;t++) acc[t] = (f32x4){0.f,0.f,0.f,0.f};
#pragma unroll
            for (int kt=0;kt<2;kt++)
#pragma unroll
                for (int t=0;t<OT;t++)
                    acc[t] = __builtin_amdgcn_mfma_f32_16x16x32_bf16(af[kt], bf[t][kt], acc[t], 0,0,0);
#pragma unroll
            for (int t=0;t<OT;t++){
#pragma unroll
                for (int r=0;r<4;r++){
                    float h = acc[t][r] + brow[t];
                    float x = fmaxf(h*oA[t]+oB[t], 0.f);
                    vmax[t] = fmaxf(vmax[t], x);
                }
            }
        }
#pragma unroll
        for (int t=0;t<OT;t++){
            float v = vmax[t];
            v = fmaxf(v, __shfl_xor(v,16,64));
            v = fmaxf(v, __shfl_xor(v,32,64));
            if (quad==0){
                int o = t*16+col, bb = grp>>10, ss = grp&1023;
                out1[((size_t)bb*128+o)*NSP + ss] = v;
            }
        }
    }
}

// ---------------------------------------------------------------- weight prep (f32 -> bf16, pad K)
__global__ void prep_kernel(const float* __restrict__ w0, const float* __restrict__ w1,
    const float* __restrict__ w2, unsigned short* __restrict__ wp0,
    unsigned short* __restrict__ wp1, unsigned short* __restrict__ wp2)
{
    int t = blockIdx.x*256 + threadIdx.x;
    if (t < 64*32){ int o=t>>5, c=t&31; wp0[t] = (c<9) ? f2bf(w0[o*9+c]) : (unsigned short)0; }
    if (t < 64*64)  wp1[t] = f2bf(w1[t]);
    if (t < 128*64) wp2[t] = f2bf(w2[t]);
}

extern "C" void kernel_launch(void* const* d_in, const int* in_sizes, int n_in,
                              void* d_out, int out_size, void* d_ws, size_t ws_size,
                              hipStream_t stream)
{
    (void)in_sizes; (void)n_in; (void)out_size; (void)ws_size;
    const float* xyz = (const float*)d_in[0];
    const float* pts = (const float*)d_in[1];
    const float* w0  = (const float*)d_in[2];
    const float* b0  = (const float*)d_in[3];
    const float* g0  = (const float*)d_in[4];
    const float* be0 = (const float*)d_in[5];
    const float* w1  = (const float*)d_in[6];
    const float* b1  = (const float*)d_in[7];
    const float* g1  = (const float*)d_in[8];
    const float* be1 = (const float*)d_in[9];
    const float* w2  = (const float*)d_in[10];
    const float* b2  = (const float*)d_in[11];
    const float* g2  = (const float*)d_in[12];
    const float* be2 = (const float*)d_in[13];

    char* ws = (char*)d_ws;
    size_t off = 0;
    auto alloc = [&](size_t sz)->char*{ char* p = ws + off; off = (off + sz + 255) & ~(size_t)255; return p; };
    unsigned short* wp0     = (unsigned short*)alloc(64*32*2);
    unsigned short* wp1     = (unsigned short*)alloc(64*64*2);
    unsigned short* wp2     = (unsigned short*)alloc(128*64*2);
    double*         stats   = (double*)        alloc((size_t)3*8*2*128*8);   // 49152 B (256-aligned)
    unsigned*       progress= (unsigned*)      alloc((size_t)16*16*4);        // directly after stats
    unsigned long long* pubXY = (unsigned long long*)alloc((size_t)NB*NSP*8);
    unsigned*       pubZ    = (unsigned*)      alloc((size_t)NB*NSP*4);
    unsigned short* feat    = (unsigned short*)alloc((size_t)PTOT*32*2);
    unsigned short* h1      = (unsigned short*)alloc((size_t)PTOT*64*2);

    float* out0 = (float*)d_out;
    float* out1 = out0 + (size_t)NB*3*NSP;

    // one memset covers stats (49152) + progress (1024): contiguous in ws
    hipMemsetAsync(stats, 0, (size_t)3*8*2*128*8 + 16*16*4, stream);
    prep_kernel<<<32,256,0,stream>>>(w0,w1,w2,wp0,wp1,wp2);
    // fused FPS + gather: dedicated fps CUs + batched publish + poll backoff
    fps_gather_kernel<<<GRID_FG,256,0,stream>>>(xyz, pts, out0, feat, pubXY, pubZ, progress);
    // stats0 only — h0 is never written to HBM
    conv_kernel<1,4,false,false><<<1024,256,0,stream>>>(feat, wp0, b0, nullptr, nullptr, nullptr, nullptr, stats);
    // fused layer0+layer1 with in-LDS transpose
    conv01_kernel<<<1024,256,0,stream>>>(feat, wp0, b0, stats, g0, be0, wp1, b1, h1, stats + 2048);
    // layer2 stats
    conv_kernel<2,8,true,false><<<1024,256,0,stream>>>(h1, wp2, b2, stats + 2048, g1, be1, nullptr, stats + 4096);
    conv_final_kernel<<<2048,256,0,stream>>>(h1, wp2, b2, stats + 2048, g1, be1, stats + 4096, g2, be2, out1);
}

// Round 16
// 859.409 us; speedup vs baseline: 1.0456x; 1.0456x over previous
//
#include <hip/hip_runtime.h>
#include <hip/hip_bf16.h>
#include <stdint.h>

#define NB 16
#define NP 4096
#define NSP 1024      // npoint
#define KNN 32        // nsample
#define PTOT (NB*NSP*KNN)      // 524288 rows
#define NTILES (PTOT/16)       // 32768 M-tiles

typedef __attribute__((ext_vector_type(8))) short short8;
typedef __attribute__((ext_vector_type(4))) float f32x4;
typedef __attribute__((ext_vector_type(2))) float f32x2;

__device__ __forceinline__ float fadd_(float a,float b){return __fadd_rn(a,b);}
__device__ __forceinline__ float fmul_(float a,float b){return __fmul_rn(a,b);}
__device__ __forceinline__ float fsub_(float a,float b){return __fsub_rn(a,b);}

__device__ __forceinline__ float bf2f(unsigned short u){
    unsigned int x = ((unsigned int)u) << 16; float f; __builtin_memcpy(&f,&x,4); return f;
}
__device__ __forceinline__ unsigned short f2bf(float f){
    unsigned int x; __builtin_memcpy(&x,&f,4);
    x = x + 0x7fffu + ((x>>16)&1u);
    return (unsigned short)(x>>16);
}

// f32 max step via DPP (identity 0 for invalid lanes is safe: distances >= 0).
template<int CTRL>
__device__ __forceinline__ float dpp_fmax_step(float v){
    int d = __builtin_amdgcn_update_dpp(0, __float_as_int(v), CTRL, 0xF, 0xF, true);
    return fmaxf(v, __int_as_float(d));
}

// per-channel BN stats -> (A, B); verbatim the retired finalize_kernel math.
__device__ __forceinline__ void ab_from_stats(const double* __restrict__ st, const float* __restrict__ g,
    const float* __restrict__ beta, int o, float* A_out, float* B_out)
{
    double s=0.0, q=0.0;
#pragma unroll
    for (int slot=0;slot<8;slot++){
        s += st[(size_t)(slot*2+0)*128+o];
        q += st[(size_t)(slot*2+1)*128+o];
    }
    const double cnt = (double)PTOT;
    float mean = (float)(s/cnt);
    float var  = (float)(q/cnt - (s/cnt)*(s/cnt));
    float inv  = rsqrtf(var + 1e-5f);
    float A = g[o]*inv;
    *A_out = A; *B_out = beta[o] - mean*A;
}

// ---------------------------------------------------------------- FPS v10 (frozen)
// Verified v5 body + lds_far stash + fused centroid epilogue. 10 rounds of
// evidence: the ~600-cyc/step serial chain is irreducible in this structure,
// and any concurrent chip activity slows it (overlap attempts all regressed).
__global__ __launch_bounds__(256,1) void fps_kernel(const float* __restrict__ xyz,
    float* __restrict__ new_xyz, float* __restrict__ out0)
{
    const int b = blockIdx.x, tid = threadIdx.x;
    const int lane = tid & 63, wv = tid >> 6;
    const float* xb = xyz + (size_t)b*3*NP;
    __shared__ float4 sp[NP];                       // 64 KB, (x,y,z,0)
    __shared__ unsigned long long slots[2][4];
    __shared__ int lds_far[NSP];
    f32x2 px[8], py[8], pz[8], pd2[8];
    const int base = tid*16;
#pragma unroll
    for (int j=0;j<16;j+=4){
        float4 vx = *(const float4*)(xb + base + j);
        float4 vy = *(const float4*)(xb + NP + base + j);
        float4 vz = *(const float4*)(xb + 2*NP + base + j);
        px[j/2]   = (f32x2){vx.x,vx.y}; px[j/2+1] = (f32x2){vx.z,vx.w};
        py[j/2]   = (f32x2){vy.x,vy.y}; py[j/2+1] = (f32x2){vy.z,vy.w};
        pz[j/2]   = (f32x2){vz.x,vz.y}; pz[j/2+1] = (f32x2){vz.z,vz.w};
        sp[base+j+0] = make_float4(vx.x,vy.x,vz.x,0.f);
        sp[base+j+1] = make_float4(vx.y,vy.y,vz.y,0.f);
        sp[base+j+2] = make_float4(vx.z,vy.z,vz.z,0.f);
        sp[base+j+3] = make_float4(vx.w,vy.w,vz.w,0.f);
        pd2[j/2]   = (f32x2){1e10f,1e10f};
        pd2[j/2+1] = (f32x2){1e10f,1e10f};
    }
    __syncthreads();
    int far = 0;
    float cx, cy, cz;
    { float4 c0 = sp[0]; cx=c0.x; cy=c0.y; cz=c0.z; }
    for (int s=0;s<NSP;s++){
        if (tid == (s & 255)) lds_far[s] = far;
        f32x2 bm2 = (f32x2){-1.f,-1.f};
        {
#pragma clang fp contract(off)
            const f32x2 cx2 = (f32x2){cx,cx}, cy2 = (f32x2){cy,cy}, cz2 = (f32x2){cz,cz};
#pragma unroll
            for (int k=0;k<8;k++){
                f32x2 dx = px[k]-cx2, dy = py[k]-cy2, dz = pz[k]-cz2;
                f32x2 d  = (dx*dx + dy*dy) + dz*dz;
                pd2[k] = __builtin_elementwise_min(pd2[k], d);
                bm2    = __builtin_elementwise_max(bm2, pd2[k]);
            }
        }
        float bd = fmaxf(bm2.x, bm2.y);
        float m = bd;
        m = dpp_fmax_step<0x111>(m);   // row_shr:1
        m = dpp_fmax_step<0x112>(m);   // row_shr:2
        m = dpp_fmax_step<0x114>(m);   // row_shr:4
        m = dpp_fmax_step<0x118>(m);   // row_shr:8
        m = dpp_fmax_step<0x142>(m);   // row_bcast:15
        m = dpp_fmax_step<0x143>(m);   // row_bcast:31  -> lane 63 has wave max
        const float wm = __int_as_float(__builtin_amdgcn_readlane(__float_as_int(m), 63));
        int il = 0;
#pragma unroll
        for (int k=7;k>=0;k--){
            if (pd2[k].y == wm) il = 2*k+1;
            if (pd2[k].x == wm) il = 2*k;
        }
        unsigned long long wmask = __ballot(bd == wm);   // nonempty by construction
        int L = __ffsll(wmask) - 1;                      // lowest lane = smallest idx
        int widx = __builtin_amdgcn_readlane(base + il, L);
        unsigned long long key = ((unsigned long long)__float_as_uint(wm) << 32)
                               | (unsigned int)(NP-1-widx);
        if (lane==0) slots[s&1][wv] = key;
        __syncthreads();
        {
            const unsigned long long* sl = slots[s&1];
            unsigned long long a0 = sl[0], a1 = sl[1], a2 = sl[2], a3 = sl[3];
            unsigned long long m0 = a0>a1?a0:a1, m1 = a2>a3?a2:a3;
            unsigned long long mx = m0>m1?m0:m1;
            far = NP-1-(int)(mx & 0xFFFFFFFFu);
        }
        float4 c = sp[far]; cx=c.x; cy=c.y; cz=c.z;
    }
    __syncthreads();
    for (int i=tid;i<NSP;i+=256){
        int id = lds_far[i];
        float4 c = sp[id];
        float* nz = new_xyz + ((size_t)b*NSP + i)*3;
        nz[0]=c.x; nz[1]=c.y; nz[2]=c.z;
        out0[(size_t)b*3*NSP + i]         = c.x;
        out0[(size_t)b*3*NSP + NSP + i]   = c.y;
        out0[(size_t)b*3*NSP + 2*NSP + i] = c.z;
    }
}

// ---------------------------------------------------------------- ball query + gather
__global__ __launch_bounds__(256,1) void ball_gather_kernel(const float* __restrict__ xyz,
    const float* __restrict__ pts, const float* __restrict__ new_xyz,
    unsigned short* __restrict__ feat)
{
    const int lane = threadIdx.x & 63, wv = threadIdx.x >> 6;
    const int center = blockIdx.x*4 + wv;
    const int b = center >> 10;
    const float* xb = xyz + (size_t)b*3*NP;
    const float* pb = pts + (size_t)b*6*NP;
    const float* nz = new_xyz + (size_t)center*3;
    const float cx=nz[0], cy=nz[1], cz=nz[2];
    const float src2 = fadd_(fadd_(fmul_(cx,cx),fmul_(cy,cy)),fmul_(cz,cz));
    const float R2 = (float)(0.4*0.4);   // must round via double: 0.4f*0.4f is a different float!
    __shared__ int slots[4][32];
    int total = 0;
    for (int c0=0;c0<NP;c0+=64){
        const int i = c0 + lane;
        float x=xb[i], y=xb[NP+i], z=xb[2*NP+i];
        float dot  = fadd_(fadd_(fmul_(cx,x),fmul_(cy,y)),fmul_(cz,z));
        float dst2 = fadd_(fadd_(fmul_(x,x),fmul_(y,y)),fmul_(z,z));
        float d = fadd_(fadd_(fmul_(-2.0f,dot), src2), dst2);
        bool pred = !(d > R2);
        unsigned long long m = __ballot(pred);
        int pos = total + (int)__popcll(m & ((1ull<<lane)-1ull));
        if (pred && pos < 32) slots[wv][pos] = i;
        total += (int)__popcll(m);
        if (total >= 32) break;
    }
    const int nvalid = total < 32 ? total : 32;
    const int n = lane & 31;
    const int idx = slots[wv][ (n < nvalid) ? n : 0 ];
    unsigned short* fr = feat + (size_t)center*KNN*32 + (size_t)n*32;
    if (lane < 32){
        float gx = fsub_(xb[idx], cx), gy = fsub_(xb[NP+idx], cy), gz = fsub_(xb[2*NP+idx], cz);
        float p0=pb[idx], p1=pb[NP+idx], p2=pb[2*NP+idx], p3=pb[3*NP+idx], p4=pb[4*NP+idx];
        short8 v;
        v[0]=(short)f2bf(gx); v[1]=(short)f2bf(gy); v[2]=(short)f2bf(gz);
        v[3]=(short)f2bf(p0); v[4]=(short)f2bf(p1); v[5]=(short)f2bf(p2);
        v[6]=(short)f2bf(p3); v[7]=(short)f2bf(p4);
        *(short8*)fr = v;
    } else {
        float p5 = pb[5*NP+idx];
        short8 v = (short8){0,0,0,0,0,0,0,0};
        v[0]=(short)f2bf(p5);
        *(short8*)(fr+8)  = v;
        short8 z8 = (short8){0,0,0,0,0,0,0,0};
        *(short8*)(fr+16) = z8;
        *(short8*)(fr+24) = z8;
    }
}

// ---------------------------------------------------------------- conv + stats (MFMA)
// h = in@W^T + bias. Optional input normalization relu(x*A+B) fused in prologue,
// with (A,B) computed in-kernel from the previous layer's stats.
template<int KT,int OT,bool NORM_IN,bool STORE_H>
__global__ __launch_bounds__(256,1) void conv_kernel(const unsigned short* __restrict__ in,
    const unsigned short* __restrict__ wp, const float* __restrict__ bias,
    const double* __restrict__ stats_in, const float* __restrict__ gin,
    const float* __restrict__ bein,
    unsigned short* __restrict__ h_out, double* __restrict__ stats)
{
    constexpr int K = KT*32, O = OT*16;
    const int lane = threadIdx.x & 63, wv = threadIdx.x >> 6;
    const int col = lane & 15, quad = lane >> 4;
    __shared__ float sA[128], sB[128];
    if constexpr (NORM_IN){
        if ((int)threadIdx.x < K){
            float A, B;
            ab_from_stats(stats_in, gin, bein, threadIdx.x, &A, &B);
            sA[threadIdx.x] = A; sB[threadIdx.x] = B;
        }
        __syncthreads();
    }
    short8 bf[OT][KT];
#pragma unroll
    for (int t=0;t<OT;t++)
#pragma unroll
        for (int kt=0;kt<KT;kt++)
            bf[t][kt] = *(const short8*)(wp + (size_t)(t*16+col)*K + kt*32 + quad*8);
    float brow[OT];
#pragma unroll
    for (int t=0;t<OT;t++) brow[t] = bias[t*16+col];
    float nA[KT*8], nB[KT*8];
    if constexpr (NORM_IN){
#pragma unroll
        for (int kt=0;kt<KT;kt++)
#pragma unroll
            for (int j=0;j<8;j++){
                int c = kt*32+quad*8+j;
                nA[kt*8+j]=sA[c]; nB[kt*8+j]=sB[c];
            }
    }
    float ssum[OT], ssq[OT];
#pragma unroll
    for (int t=0;t<OT;t++){ ssum[t]=0.f; ssq[t]=0.f; }
    const int gw = blockIdx.x*4 + wv, nw = gridDim.x*4;
    for (int tile=gw; tile<NTILES; tile+=nw){
        const int row0 = tile*16;
        short8 af[KT];
#pragma unroll
        for (int kt=0;kt<KT;kt++){
            af[kt] = *(const short8*)(in + (size_t)(row0+col)*K + kt*32 + quad*8);
            if constexpr (NORM_IN){
#pragma unroll
                for (int j=0;j<8;j++){
                    float x = bf2f((unsigned short)af[kt][j]);
                    x = fmaxf(x*nA[kt*8+j]+nB[kt*8+j], 0.f);
                    af[kt][j] = (short)f2bf(x);
                }
            }
        }
        f32x4 acc[OT];
#pragma unroll
        for (int t=0;t<OT;t++) acc[t] = (f32x4){0.f,0.f,0.f,0.f};
#pragma unroll
        for (int kt=0;kt<KT;kt++)
#pragma unroll
            for (int t=0;t<OT;t++)
                acc[t] = __builtin_amdgcn_mfma_f32_16x16x32_bf16(af[kt], bf[t][kt], acc[t], 0,0,0);
#pragma unroll
        for (int t=0;t<OT;t++){
#pragma unroll
            for (int r=0;r<4;r++){
                float h = acc[t][r] + brow[t];
                if constexpr (STORE_H)
                    h_out[(size_t)(row0 + quad*4 + r)*O + t*16 + col] = f2bf(h);
                ssum[t] += h; ssq[t] = fmaf(h,h,ssq[t]);
            }
        }
    }
    __shared__ float bsum[128], bssq[128];
    for (int i=threadIdx.x;i<128;i+=256){ bsum[i]=0.f; bssq[i]=0.f; }
    __syncthreads();
#pragma unroll
    for (int t=0;t<OT;t++){
        float v = ssum[t]; v += __shfl_xor(v,16,64); v += __shfl_xor(v,32,64);
        float q = ssq[t];  q += __shfl_xor(q,16,64); q += __shfl_xor(q,32,64);
        if (quad==0){ atomicAdd(&bsum[t*16+col], v); atomicAdd(&bssq[t*16+col], q); }
    }
    __syncthreads();
    if ((int)threadIdx.x < O){
        const int slot = blockIdx.x & 7;
        atomicAdd(&stats[(size_t)(slot*2+0)*128 + threadIdx.x], (double)bsum[threadIdx.x]);
        atomicAdd(&stats[(size_t)(slot*2+1)*128 + threadIdx.x], (double)bssq[threadIdx.x]);
    }
}

// ---------------------------------------------------------------- fused layer0+layer1 (h0 never touches HBM)
// Recomputes h0 = feat@W0^T + b0 (bit-identical MFMA), replicates the exact
// f2bf->bf2f double rounding the old HBM round-trip performed, applies
// norm0+relu, transposes C-layout -> A-fragment layout through a per-wave
// LDS scratch ([16][72] ushort; 72-pad makes the b128 A-frag reads hit the
// conflict-free 8-phase minimum), then layer1 MFMA + h1 store + stats1.
__global__ __launch_bounds__(256,1) void conv01_kernel(
    const unsigned short* __restrict__ feat,
    const unsigned short* __restrict__ wp0, const float* __restrict__ b0v,
    const double* __restrict__ stats0, const float* __restrict__ g0v,
    const float* __restrict__ be0v,
    const unsigned short* __restrict__ wp1, const float* __restrict__ b1v,
    unsigned short* __restrict__ h1_out, double* __restrict__ stats1)
{
    const int lane = threadIdx.x & 63, wv = threadIdx.x >> 6;
    const int col = lane & 15, quad = lane >> 4;
    __shared__ float sA[64], sB[64];
    __shared__ unsigned short scratch[4][16*72];    // per-wave 16 rows x 72 ch (pad)
    if ((int)threadIdx.x < 64){
        float A, B;
        ab_from_stats(stats0, g0v, be0v, threadIdx.x, &A, &B);
        sA[threadIdx.x] = A; sB[threadIdx.x] = B;
    }
    __syncthreads();
    short8 bf0[4];
#pragma unroll
    for (int t=0;t<4;t++)
        bf0[t] = *(const short8*)(wp0 + (size_t)(t*16+col)*32 + quad*8);
    short8 bf1[4][2];
#pragma unroll
    for (int t=0;t<4;t++)
#pragma unroll
        for (int kt=0;kt<2;kt++)
            bf1[t][kt] = *(const short8*)(wp1 + (size_t)(t*16+col)*64 + kt*32 + quad*8);
    float b0row[4], n0A[4], n0B[4], b1row[4];
#pragma unroll
    for (int t=0;t<4;t++){
        b0row[t] = b0v[t*16+col];
        n0A[t]   = sA[t*16+col];
        n0B[t]   = sB[t*16+col];
        b1row[t] = b1v[t*16+col];
    }
    float ssum[4], ssq[4];
#pragma unroll
    for (int t=0;t<4;t++){ ssum[t]=0.f; ssq[t]=0.f; }
    unsigned short* sw = scratch[wv];
    const int gw = blockIdx.x*4 + wv, nw = gridDim.x*4;
    for (int tile=gw; tile<NTILES; tile+=nw){
        const int row0 = tile*16;
        // layer0: feat tile (16 rows x 32 ch), A-frag direct from global
        short8 af0 = *(const short8*)(feat + (size_t)(row0+col)*32 + quad*8);
        f32x4 acc0[4];
#pragma unroll
        for (int t=0;t<4;t++) acc0[t] = (f32x4){0.f,0.f,0.f,0.f};
#pragma unroll
        for (int t=0;t<4;t++)
            acc0[t] = __builtin_amdgcn_mfma_f32_16x16x32_bf16(af0, bf0[t], acc0[t], 0,0,0);
        // bias + EXACT old rounding (h0 was stored bf16) + norm0 + relu -> LDS
#pragma unroll
        for (int t=0;t<4;t++)
#pragma unroll
            for (int r=0;r<4;r++){
                float h = acc0[t][r] + b0row[t];
                unsigned short hb = f2bf(h);               // = old h0 store
                float x = fmaxf(bf2f(hb)*n0A[t] + n0B[t], 0.f);
                sw[(quad*4+r)*72 + t*16 + col] = f2bf(x);  // = old conv2 repack
            }
        // layer1 A-frags from LDS (wave-private; compiler inserts lgkmcnt)
        short8 af1[2];
        af1[0] = *(const short8*)(&sw[(size_t)col*72 + quad*8]);
        af1[1] = *(const short8*)(&sw[(size_t)col*72 + 32 + quad*8]);
        f32x4 acc1[4];
#pragma unroll
        for (int t=0;t<4;t++) acc1[t] = (f32x4){0.f,0.f,0.f,0.f};
#pragma unroll
        for (int kt=0;kt<2;kt++)
#pragma unroll
            for (int t=0;t<4;t++)
                acc1[t] = __builtin_amdgcn_mfma_f32_16x16x32_bf16(af1[kt], bf1[t][kt], acc1[t], 0,0,0);
#pragma unroll
        for (int t=0;t<4;t++)
#pragma unroll
            for (int r=0;r<4;r++){
                float h = acc1[t][r] + b1row[t];
                h1_out[(size_t)(row0 + quad*4 + r)*64 + t*16 + col] = f2bf(h);
                ssum[t] += h; ssq[t] = fmaf(h,h,ssq[t]);
            }
    }
    __shared__ float bsum[64], bssq[64];
    for (int i=threadIdx.x;i<64;i+=256){ bsum[i]=0.f; bssq[i]=0.f; }
    __syncthreads();
#pragma unroll
    for (int t=0;t<4;t++){
        float v = ssum[t]; v += __shfl_xor(v,16,64); v += __shfl_xor(v,32,64);
        float q = ssq[t];  q += __shfl_xor(q,16,64); q += __shfl_xor(q,32,64);
        if (quad==0){ atomicAdd(&bsum[t*16+col], v); atomicAdd(&bssq[t*16+col], q); }
    }
    __syncthreads();
    if ((int)threadIdx.x < 64){
        const int slot = blockIdx.x & 7;
        atomicAdd(&stats1[(size_t)(slot*2+0)*128 + threadIdx.x], (double)bsum[threadIdx.x]);
        atomicAdd(&stats1[(size_t)(slot*2+1)*128 + threadIdx.x], (double)bssq[threadIdx.x]);
    }
}

// ---------------------------------------------------------------- layer2 recompute + norm + relu + maxpool
__global__ __launch_bounds__(256,1) void conv_final_kernel(const unsigned short* __restrict__ in,
    const unsigned short* __restrict__ wp, const float* __restrict__ bias,
    const double* __restrict__ stats1, const float* __restrict__ g1v,
    const float* __restrict__ be1v,
    const double* __restrict__ stats2, const float* __restrict__ g2v,
    const float* __restrict__ be2v,
    float* __restrict__ out1)
{
    constexpr int KT=2, OT=8, K=64;
    const int lane = threadIdx.x & 63, wv = threadIdx.x >> 6;
    const int col = lane & 15, quad = lane >> 4;
    __shared__ float sInA[64], sInB[64], sOutA[128], sOutB[128];
    {
        const int t0 = threadIdx.x;
        if (t0 < 128){
            float A, B;
            ab_from_stats(stats2, g2v, be2v, t0, &A, &B);
            sOutA[t0] = A; sOutB[t0] = B;
        } else if (t0 < 192){
            float A, B;
            ab_from_stats(stats1, g1v, be1v, t0-128, &A, &B);
            sInA[t0-128] = A; sInB[t0-128] = B;
        }
        __syncthreads();
    }
    short8 bf[OT][KT];
#pragma unroll
    for (int t=0;t<OT;t++)
#pragma unroll
        for (int kt=0;kt<KT;kt++)
            bf[t][kt] = *(const short8*)(wp + (size_t)(t*16+col)*K + kt*32 + quad*8);
    float brow[OT], oA[OT], oB[OT];
#pragma unroll
    for (int t=0;t<OT;t++){
        brow[t] = bias[t*16+col];
        oA[t] = sOutA[t*16+col];
        oB[t] = sOutB[t*16+col];
    }
    float nA[16], nB[16];
#pragma unroll
    for (int kt=0;kt<2;kt++)
#pragma unroll
        for (int j=0;j<8;j++){
            int c = kt*32+quad*8+j;
            nA[kt*8+j]=sInA[c]; nB[kt*8+j]=sInB[c];
        }
    const int gw = blockIdx.x*4 + wv, nw = gridDim.x*4;
    for (int grp=gw; grp<NB*NSP; grp+=nw){
        float vmax[OT];
#pragma unroll
        for (int t=0;t<OT;t++) vmax[t]=0.f;
#pragma unroll
        for (int mt=0; mt<2; mt++){
            const int row0 = grp*32 + mt*16;
            short8 af[KT];
#pragma unroll
            for (int kt=0;kt<2;kt++){
                af[kt] = *(const short8*)(in + (size_t)(row0+col)*K + kt*32 + quad*8);
#pragma unroll
                for (int j=0;j<8;j++){
                    float x = bf2f((unsigned short)af[kt][j]);
                    x = fmaxf(x*nA[kt*8+j]+nB[kt*8+j], 0.f);
                    af[kt][j] = (short)f2bf(x);
                }
            }
            f32x4 acc[OT];
#pragma unroll
            for (int t=0;t<OT;t++) acc[t] = (f32x4){0.f,0.f,0.f,0.f};
#pragma unroll
            for (int kt=0;kt<2;kt++)
#pragma unroll
                for (int t=0;t<OT;t++)
                    acc[t] = __builtin_amdgcn_mfma_f32_16x16x32_bf16(af[kt], bf[t][kt], acc[t], 0,0,0);
#pragma unroll
            for (int t=0;t<OT;t++){
#pragma unroll
                for (int r=0;r<4;r++){
                    float h = acc[t][r] + brow[t];
                    float x = fmaxf(h*oA[t]+oB[t], 0.f);
                    vmax[t] = fmaxf(vmax[t], x);
                }
            }
        }
#pragma unroll
        for (int t=0;t<OT;t++){
            float v = vmax[t];
            v = fmaxf(v, __shfl_xor(v,16,64));
            v = fmaxf(v, __shfl_xor(v,32,64));
            if (quad==0){
                int o = t*16+col, bb = grp>>10, ss = grp&1023;
                out1[((size_t)bb*128+o)*NSP + ss] = v;
            }
        }
    }
}

// ---------------------------------------------------------------- weight prep (f32 -> bf16, pad K)
__global__ void prep_kernel(const float* __restrict__ w0, const float* __restrict__ w1,
    const float* __restrict__ w2, unsigned short* __restrict__ wp0,
    unsigned short* __restrict__ wp1, unsigned short* __restrict__ wp2)
{
    int t = blockIdx.x*256 + threadIdx.x;
    if (t < 64*32){ int o=t>>5, c=t&31; wp0[t] = (c<9) ? f2bf(w0[o*9+c]) : (unsigned short)0; }
    if (t < 64*64)  wp1[t] = f2bf(w1[t]);
    if (t < 128*64) wp2[t] = f2bf(w2[t]);
}

extern "C" void kernel_launch(void* const* d_in, const int* in_sizes, int n_in,
                              void* d_out, int out_size, void* d_ws, size_t ws_size,
                              hipStream_t stream)
{
    (void)in_sizes; (void)n_in; (void)out_size; (void)ws_size;
    const float* xyz = (const float*)d_in[0];
    const float* pts = (const float*)d_in[1];
    const float* w0  = (const float*)d_in[2];
    const float* b0  = (const float*)d_in[3];
    const float* g0  = (const float*)d_in[4];
    const float* be0 = (const float*)d_in[5];
    const float* w1  = (const float*)d_in[6];
    const float* b1  = (const float*)d_in[7];
    const float* g1  = (const float*)d_in[8];
    const float* be1 = (const float*)d_in[9];
    const float* w2  = (const float*)d_in[10];
    const float* b2  = (const float*)d_in[11];
    const float* g2  = (const float*)d_in[12];
    const float* be2 = (const float*)d_in[13];

    char* ws = (char*)d_ws;
    size_t off = 0;
    auto alloc = [&](size_t sz)->char*{ char* p = ws + off; off = (off + sz + 255) & ~(size_t)255; return p; };
    float*          new_xyz = (float*)         alloc((size_t)NB*NSP*3*4);
    unsigned short* wp0     = (unsigned short*)alloc(64*32*2);
    unsigned short* wp1     = (unsigned short*)alloc(64*64*2);
    unsigned short* wp2     = (unsigned short*)alloc(128*64*2);
    double*         stats   = (double*)        alloc((size_t)3*8*2*128*8);
    unsigned short* feat    = (unsigned short*)alloc((size_t)PTOT*32*2);
    unsigned short* h1      = (unsigned short*)alloc((size_t)PTOT*64*2);

    float* out0 = (float*)d_out;
    float* out1 = out0 + (size_t)NB*3*NSP;

    hipMemsetAsync(stats, 0, (size_t)3*8*2*128*8, stream);
    prep_kernel<<<32,256,0,stream>>>(w0,w1,w2,wp0,wp1,wp2);
    fps_kernel<<<NB,256,0,stream>>>(xyz, new_xyz, out0);
    ball_gather_kernel<<<NB*NSP/4,256,0,stream>>>(xyz, pts, new_xyz, feat);
    // stats0 only — h0 is never written to HBM
    conv_kernel<1,4,false,false><<<1024,256,0,stream>>>(feat, wp0, b0, nullptr, nullptr, nullptr, nullptr, stats);
    // fused layer0+layer1 with in-LDS transpose
    conv01_kernel<<<1024,256,0,stream>>>(feat, wp0, b0, stats, g0, be0, wp1, b1, h1, stats + 2048);
    // layer2 stats
    conv_kernel<2,8,true,false><<<1024,256,0,stream>>>(h1, wp2, b2, stats + 2048, g1, be1, nullptr, stats + 4096);
    conv_final_kernel<<<2048,256,0,stream>>>(h1, wp2, b2, stats + 2048, g1, be1, stats + 4096, g2, be2, out1);
}